// Round 4
// baseline (536.980 us; speedup 1.0000x reference)
//
#include <hip/hip_runtime.h>
#include <math.h>

// NNFM loss on MI355X.
// loss = mean_i (1 - max_j (xhat_i . shat_j)),  xhat/shat = column-normalized feats.
// R2: XOR-swizzled LDS -> bank conflicts 1.5e8 -> 0 (475us).
// R3: 256^2 tile, 8 waves, phase-split + counted vmcnt + setprio (465us, lockstep-serial).
// R4: one-phase-ahead fragment read pipeline (8 phases / 2 K-tiles, content-addressed
//     register sets), 1 barrier per phase, reads overlap MFMA execution.

#define C_DIM 768
#define P_DIM 16384
#define KT 12           // K-tiles (BK=64) per j-tile: 768/64
#define NJT 16          // j-tiles per block: (P/JSPLIT)/256
#define JSPLIT 4
#define EPSF 1e-8f

typedef __bf16 bf16;
typedef bf16 bf16x8 __attribute__((ext_vector_type(8)));
typedef float f32x4 __attribute__((ext_vector_type(4)));

// workspace layout (bytes)
#define OFF_XN   0
#define OFF_SN   25165824UL                 // 16384*768*2
#define OFF_INVX 50331648UL
#define OFF_INVS 50397184UL
#define OFF_MAX  50462720UL                 // 4 * 16384 * 4

__device__ __forceinline__ void async_copy16(const void* gsrc, void* ldst) {
    __builtin_amdgcn_global_load_lds(
        (const __attribute__((address_space(1))) void*)gsrc,
        (__attribute__((address_space(3))) void*)ldst,
        16, 0, 0);
}

// phase end: drain all but the newest stage-half (2 loads), complete own ds_reads,
// then publish via barrier. lgkmcnt(0) closes the ds_read-vs-next-DMA-landing race.
#define VMBAR() { asm volatile("s_waitcnt vmcnt(2) lgkmcnt(0)" ::: "memory"); \
                  __builtin_amdgcn_s_barrier(); }

// --- 1. column L2 norms (inverse, +eps) for both inputs ---
__global__ void norm_kernel(const float* __restrict__ x, const float* __restrict__ s,
                            float* __restrict__ invx, float* __restrict__ invs) {
    const float4* src = (const float4*)(blockIdx.y == 0 ? x : s);
    float* dst = (blockIdx.y == 0) ? invx : invs;
    int j4 = blockIdx.x * 256 + threadIdx.x;
    float sx = 0.f, sy = 0.f, sz = 0.f, sw = 0.f;
    for (int c = 0; c < C_DIM; ++c) {
        float4 v = src[c * (P_DIM / 4) + j4];
        sx += v.x * v.x; sy += v.y * v.y; sz += v.z * v.z; sw += v.w * v.w;
    }
    int j = j4 * 4;
    dst[j + 0] = 1.0f / (sqrtf(sx) + EPSF);
    dst[j + 1] = 1.0f / (sqrtf(sy) + EPSF);
    dst[j + 2] = 1.0f / (sqrtf(sz) + EPSF);
    dst[j + 3] = 1.0f / (sqrtf(sw) + EPSF);
}

// --- 2. transpose [c][p] -> [p][c], normalize, cast bf16 ---
__global__ void tnorm_kernel(const float* __restrict__ x, const float* __restrict__ s,
                             const float* __restrict__ invx, const float* __restrict__ invs,
                             bf16* __restrict__ Xn, bf16* __restrict__ Sn) {
    __shared__ float tile[64][65];
    const float* src = blockIdx.z ? s : x;
    const float* inv = blockIdx.z ? invs : invx;
    bf16* dst = blockIdx.z ? Sn : Xn;
    int c0 = blockIdx.y * 64;
    int j0 = blockIdx.x * 64;
    int t = threadIdx.x;
    #pragma unroll
    for (int it = 0; it < 16; ++it) {
        int idx = it * 256 + t;
        int cr = idx >> 6, jc = idx & 63;
        tile[cr][jc] = src[(c0 + cr) * P_DIM + j0 + jc];
    }
    __syncthreads();
    #pragma unroll
    for (int it = 0; it < 16; ++it) {
        int idx = it * 256 + t;
        int jr = idx >> 6, cc = idx & 63;
        dst[(size_t)(j0 + jr) * C_DIM + c0 + cc] = (bf16)(tile[cc][jr] * inv[j0 + jr]);
    }
}

// --- 3. 256x256-tile GEMM with fused per-row running max ---
__global__ __launch_bounds__(512, 2) void nnfm_gemm_max(
    const bf16* __restrict__ Xn, const bf16* __restrict__ Sn,
    float* __restrict__ wmax) {
    __shared__ __align__(16) bf16 smA[2][256 * 64];
    __shared__ __align__(16) bf16 smB[2][256 * 64];

    const int bid = blockIdx.x;
    const int iblk = bid >> 2;
    const int split = bid & 3;
    const int i0 = iblk * 256;
    const int jbase = split * (P_DIM / JSPLIT);

    const int tid = threadIdx.x;
    const int lane = tid & 63;
    const int wid = tid >> 6;
    const int wr = (wid >> 2) * 128;
    const int wc = (wid & 3) * 64;
    const int lm = lane & 15;

    const int srow = wid * 8 + (lane >> 3);
    const int scol = ((lane & 7) ^ (lane >> 3)) * 8;
    const int kidx0 = (((lane >> 4) + 0) ^ (lane & 7)) * 8;
    const int kidx1 = (((lane >> 4) + 4) ^ (lane & 7)) * 8;

#define STAGE_A(kk_t, buf_t, half) { \
    _Pragma("unroll") \
    for (int ld = 0; ld < 2; ++ld) \
      async_copy16(Xn + (size_t)(i0 + (half) * 128 + ld * 64 + srow) * C_DIM + (kk_t) * 64 + scol, \
                   &smA[buf_t][((half) * 128 + ld * 64 + wid * 8) * 64]); }

#define STAGE_B(jt_t, kk_t, buf_t, half) { \
    _Pragma("unroll") \
    for (int ld = 0; ld < 2; ++ld) \
      async_copy16(Sn + (size_t)(jbase + (jt_t) * 256 + (half) * 128 + ld * 64 + srow) * C_DIM + (kk_t) * 64 + scol, \
                   &smB[buf_t][((half) * 128 + ld * 64 + wid * 8) * 64]); }

#define RD_A(SET, QH, BUF) { \
    _Pragma("unroll") \
    for (int m = 0; m < 4; ++m) { \
      SET[m][0] = *(const bf16x8*)&smA[BUF][(wr + (QH) * 64 + m * 16 + lm) * 64 + kidx0]; \
      SET[m][1] = *(const bf16x8*)&smA[BUF][(wr + (QH) * 64 + m * 16 + lm) * 64 + kidx1]; \
    } }

#define RD_B(SET, NH, BUF) { \
    _Pragma("unroll") \
    for (int n = 0; n < 2; ++n) { \
      SET[n][0] = *(const bf16x8*)&smB[BUF][(wc + (NH) * 32 + n * 16 + lm) * 64 + kidx0]; \
      SET[n][1] = *(const bf16x8*)&smB[BUF][(wc + (NH) * 32 + n * 16 + lm) * 64 + kidx1]; \
    } }

#define MQ(ASET, BSET, MH, NH, DOZERO, DORMAX) { \
    if (DOZERO) { \
      _Pragma("unroll") \
      for (int m = 0; m < 4; ++m) \
        _Pragma("unroll") \
        for (int n = 0; n < 2; ++n) \
          acc[(MH) * 4 + m][(NH) * 2 + n] = f32x4{0.f, 0.f, 0.f, 0.f}; \
    } \
    __builtin_amdgcn_s_setprio(1); \
    _Pragma("unroll") \
    for (int ks = 0; ks < 2; ++ks) \
      _Pragma("unroll") \
      for (int m = 0; m < 4; ++m) \
        _Pragma("unroll") \
        for (int n = 0; n < 2; ++n) \
          acc[(MH) * 4 + m][(NH) * 2 + n] = __builtin_amdgcn_mfma_f32_16x16x32_bf16( \
              ASET[m][ks], BSET[n][ks], acc[(MH) * 4 + m][(NH) * 2 + n], 0, 0, 0); \
    __builtin_amdgcn_s_setprio(0); \
    if (DORMAX) { \
      _Pragma("unroll") \
      for (int m = 0; m < 4; ++m) \
        _Pragma("unroll") \
        for (int r = 0; r < 4; ++r) \
          rmax[(MH) * 4 + m][r] = fmaxf(rmax[(MH) * 4 + m][r], \
              fmaxf(acc[(MH) * 4 + m][(NH) * 2 + 0][r], acc[(MH) * 4 + m][(NH) * 2 + 1][r])); \
    } }

    f32x4 acc[8][4];
    float rmax[8][4];
    bf16x8 aLo[4][2], aHi[4][2], Bn0[2][2], Bn1[2][2];
    #pragma unroll
    for (int m = 0; m < 8; ++m)
        #pragma unroll
        for (int r = 0; r < 4; ++r) rmax[m][r] = -3.0e38f;

    // prologue: tile 0 complete + A(1)lo + B(1)lo; drain tile 0 (8 loads) -> vmcnt(4)
    STAGE_A(0, 0, 0); STAGE_A(0, 0, 1);
    STAGE_B(0, 0, 0, 0); STAGE_B(0, 0, 0, 1);
    STAGE_A(1, 1, 0);
    STAGE_B(0, 1, 1, 0);
    asm volatile("s_waitcnt vmcnt(4)" ::: "memory");
    __builtin_amdgcn_s_barrier();
    RD_A(aLo, 0, 0)
    RD_B(Bn0, 0, 0)

    for (int jt = 0; jt < NJT; ++jt) {
        for (int it = 0; it < 6; ++it) {
            const int e = it * 2;
            int kA2 = e + 2, jt2 = jt;
            if (kA2 == KT) { kA2 = 0; jt2 = (jt + 1) & (NJT - 1); }
            int kA3 = e + 3, jt3 = jt;
            if (kA3 >= KT) { kA3 -= KT; jt3 = (jt + 1) & (NJT - 1); }
            const bool z = (it == 0), rx = (it == 5);

            // P0: tile e quad(0,0)
            STAGE_A(e + 1, 1, 1);
            MQ(aLo, Bn0, 0, 0, z, false)
            RD_B(Bn1, 1, 0)
            VMBAR();
            // P1: quad(0,1)
            STAGE_B(jt, e + 1, 1, 1);
            MQ(aLo, Bn1, 0, 1, z, false)
            RD_A(aHi, 1, 0)
            VMBAR();
            // P2: quad(1,1)
            STAGE_A(kA2, 0, 0);
            MQ(aHi, Bn1, 1, 1, z, false)
            VMBAR();
            // P3: quad(1,0)
            STAGE_A(kA2, 0, 1);
            MQ(aHi, Bn0, 1, 0, z, false)
            RD_A(aLo, 0, 1)
            RD_B(Bn0, 0, 1)
            VMBAR();
            // P4: tile o quad(0,0)
            STAGE_B(jt2, kA2, 0, 0);
            MQ(aLo, Bn0, 0, 0, false, rx)
            RD_B(Bn1, 1, 1)
            VMBAR();
            // P5: quad(0,1)
            STAGE_B(jt2, kA2, 0, 1);
            MQ(aLo, Bn1, 0, 1, false, rx)
            RD_A(aHi, 1, 1)
            VMBAR();
            // P6: quad(1,1)
            STAGE_A(kA3, 1, 0);
            MQ(aHi, Bn1, 1, 1, false, rx)
            VMBAR();
            // P7: quad(1,0)
            STAGE_B(jt3, kA3, 1, 0);
            MQ(aHi, Bn0, 1, 0, false, rx)
            RD_A(aLo, 0, 0)
            RD_B(Bn0, 0, 0)
            VMBAR();
        }
    }

    // epilogue: drain everything before reusing LDS for the reduction
    asm volatile("s_waitcnt vmcnt(0) lgkmcnt(0)" ::: "memory");
    __builtin_amdgcn_s_barrier();

    float* red = (float*)&smA[0][0];   // [4 col-waves][256 rows]
    #pragma unroll
    for (int m8 = 0; m8 < 8; ++m8)
        #pragma unroll
        for (int r = 0; r < 4; ++r) {
            float v = rmax[m8][r];
            v = fmaxf(v, __shfl_xor(v, 1));
            v = fmaxf(v, __shfl_xor(v, 2));
            v = fmaxf(v, __shfl_xor(v, 4));
            v = fmaxf(v, __shfl_xor(v, 8));
            if (lm == 0) {
                const int row_l = wr + (m8 >> 2) * 64 + (m8 & 3) * 16 + (lane >> 4) * 4 + r;
                red[(wid & 3) * 256 + row_l] = v;
            }
        }
    __builtin_amdgcn_s_barrier();
    if (tid < 256) {
        float v = fmaxf(fmaxf(red[tid], red[256 + tid]),
                        fmaxf(red[512 + tid], red[768 + tid]));
        wmax[(size_t)split * P_DIM + i0 + tid] = v;
    }
}

// --- 4. loss = mean(1 - max over 4 partials) ---
__global__ void final_reduce(const float* __restrict__ wmax, float* __restrict__ out) {
    __shared__ float red[256];
    int t = threadIdx.x;
    float sum = 0.f;
    for (int i = t; i < P_DIM; i += 256) {
        float m = wmax[i];
        #pragma unroll
        for (int sp = 1; sp < 4; ++sp) m = fmaxf(m, wmax[(size_t)sp * P_DIM + i]);
        sum += 1.0f - m;
    }
    red[t] = sum;
    __syncthreads();
    for (int st = 128; st > 0; st >>= 1) {
        if (t < st) red[t] += red[t + st];
        __syncthreads();
    }
    if (t == 0) out[0] = red[0] * (1.0f / (float)P_DIM);
}

extern "C" void kernel_launch(void* const* d_in, const int* in_sizes, int n_in,
                              void* d_out, int out_size, void* d_ws, size_t ws_size,
                              hipStream_t stream) {
    const float* x = (const float*)d_in[0];
    const float* s = (const float*)d_in[1];
    float* out = (float*)d_out;
    char* ws = (char*)d_ws;

    bf16* Xn = (bf16*)(ws + OFF_XN);
    bf16* Sn = (bf16*)(ws + OFF_SN);
    float* invx = (float*)(ws + OFF_INVX);
    float* invs = (float*)(ws + OFF_INVS);
    float* wmax = (float*)(ws + OFF_MAX);

    norm_kernel<<<dim3(16, 2), 256, 0, stream>>>(x, s, invx, invs);
    tnorm_kernel<<<dim3(256, 12, 2), 256, 0, stream>>>(x, s, invx, invs, Xn, Sn);
    nnfm_gemm_max<<<dim3((P_DIM / 256) * JSPLIT), 512, 0, stream>>>(Xn, Sn, wmax);
    final_reduce<<<1, 256, 0, stream>>>(wmax, out);
}

// Round 5
// 361.113 us; speedup vs baseline: 1.4870x; 1.4870x over previous
//
#include <hip/hip_runtime.h>
#include <math.h>

// NNFM loss on MI355X.
// loss = mean_i (1 - max_j (xhat_i . shat_j)),  xhat/shat = column-normalized feats.
// R2: XOR-swizzled LDS -> bank conflicts 1.5e8 -> 0 (475us).
// R3: 256^2 tile, 8 waves, 4-phase schedule + counted vmcnt + setprio (465us).
// R4: double-set read-ahead -> VGPR spill (WRITE_SIZE 79MB), reverted.
// R5: fp8 e4m3 operands (x64 scale), BK=128, packed-pair column permutation so
//     ds_read_b128 feeds 2 MFMA k-steps; halves LDS-read + stage + HBM bytes.

#define C_DIM 768
#define P_DIM 16384
#define KT 6            // K-tiles (BK=128) : 768/128
#define NJT 16          // j-tiles per block: (P/JSPLIT)/256
#define JSPLIT 4
#define EPSF 1e-8f
#define SCALE 64.0f

typedef unsigned char u8;
typedef float f32x4 __attribute__((ext_vector_type(4)));
typedef long i64x2 __attribute__((ext_vector_type(2)));

// workspace layout (bytes)
#define OFF_XN   0
#define OFF_SN   25165824UL
#define OFF_INVX 50331648UL
#define OFF_INVS 50397184UL
#define OFF_MAX  50462720UL                 // 4 * 16384 * 4

__device__ __forceinline__ void async_copy16(const void* gsrc, void* ldst) {
    __builtin_amdgcn_global_load_lds(
        (const __attribute__((address_space(1))) void*)gsrc,
        (__attribute__((address_space(3))) void*)ldst,
        16, 0, 0);
}

#define CFENCE() asm volatile("" ::: "memory")
#define BARRIER() { CFENCE(); __builtin_amdgcn_s_barrier(); CFENCE(); }

// --- 1. column L2 norms: inv = SCALE/(||col|| + eps) ---
__global__ void norm_kernel(const float* __restrict__ x, const float* __restrict__ s,
                            float* __restrict__ invx, float* __restrict__ invs) {
    const float4* src = (const float4*)(blockIdx.y == 0 ? x : s);
    float* dst = (blockIdx.y == 0) ? invx : invs;
    int j4 = blockIdx.x * 256 + threadIdx.x;
    float sx = 0.f, sy = 0.f, sz = 0.f, sw = 0.f;
    for (int c = 0; c < C_DIM; ++c) {
        float4 v = src[c * (P_DIM / 4) + j4];
        sx += v.x * v.x; sy += v.y * v.y; sz += v.z * v.z; sw += v.w * v.w;
    }
    int j = j4 * 4;
    dst[j + 0] = SCALE / (sqrtf(sx) + EPSF);
    dst[j + 1] = SCALE / (sqrtf(sy) + EPSF);
    dst[j + 2] = SCALE / (sqrtf(sz) + EPSF);
    dst[j + 3] = SCALE / (sqrtf(sw) + EPSF);
}

// --- 2. transpose [c][p] -> [p][c'], normalize*64, cast fp8 e4m3 ---
// Column permutation within each 128-col K-tile: byte pos = cb*16 + h*8 + o
// holds k = (cb>>2)*64 + h*32 + (cb&3)*8 + o, so a 16B read at block cb yields
// the A/B operands (8 consecutive k each) of MFMA k-steps 2*(cb>>2) (low i64)
// and 2*(cb>>2)+1 (high i64) for lane-octet cb&3.
__global__ void tnorm_kernel(const float* __restrict__ x, const float* __restrict__ s,
                             const float* __restrict__ invx, const float* __restrict__ invs,
                             u8* __restrict__ Xn, u8* __restrict__ Sn) {
    __shared__ float tile[64][65];
    const float* src = blockIdx.z ? s : x;
    const float* inv = blockIdx.z ? invs : invx;
    u8* dst = blockIdx.z ? Sn : Xn;
    int c0 = blockIdx.y * 64;
    int j0 = blockIdx.x * 64;
    int t = threadIdx.x;
    #pragma unroll
    for (int it = 0; it < 16; ++it) {
        int idx = it * 256 + t;
        int cr = idx >> 6, jc = idx & 63;
        tile[cr][jc] = src[(c0 + cr) * P_DIM + j0 + jc];
    }
    __syncthreads();
    const size_t obase = (size_t)(c0 >> 7) * 128 + ((c0 >> 6) & 1) * 64;
    #pragma unroll
    for (int it = 0; it < 2; ++it) {
        int item = it * 256 + t;
        int jr = item >> 3;
        int oct = item & 7;
        int kb = oct >> 1, h = oct & 1;
        float iv = inv[j0 + jr];
        float v[8];
        #pragma unroll
        for (int o = 0; o < 8; ++o) v[o] = tile[h * 32 + kb * 8 + o][jr] * iv;
        int lo = __builtin_amdgcn_cvt_pk_fp8_f32(v[0], v[1], 0, false);
        lo = __builtin_amdgcn_cvt_pk_fp8_f32(v[2], v[3], lo, true);
        int hi = __builtin_amdgcn_cvt_pk_fp8_f32(v[4], v[5], 0, false);
        hi = __builtin_amdgcn_cvt_pk_fp8_f32(v[6], v[7], hi, true);
        unsigned long long pk = ((unsigned long long)(unsigned int)hi << 32) | (unsigned int)lo;
        *(unsigned long long*)(dst + (size_t)(j0 + jr) * C_DIM + obase + kb * 16 + h * 8) = pk;
    }
}

// --- 3. 256x256-tile fp8 GEMM with fused per-row running max ---
// 8 waves (2M x 4N), per-wave 128x64 out; BK=128, 4 phases/K-tile, R3 lifetimes:
//  p0: A(h+1)c23  p1: B(h+1)c01  p2: B(h+1)c23  p3: A(h+2)c01 (into live buf,
//  slots dead after p2); vmcnt(2) once per K-tile at p3.
__global__ __launch_bounds__(512, 2) void nnfm_gemm_max(
    const u8* __restrict__ Xn, const u8* __restrict__ Sn,
    float* __restrict__ wmax) {
    __shared__ __align__(16) u8 smA[2][256 * 128];
    __shared__ __align__(16) u8 smB[2][256 * 128];

    const int bid = blockIdx.x;
    const int iblk = bid >> 2;
    const int split = bid & 3;
    const int i0 = iblk * 256;
    const int jbase = split * (P_DIM / JSPLIT);

    const int tid = threadIdx.x;
    const int lane = tid & 63;
    const int wid = tid >> 6;
    const int wr = (wid >> 2) * 128;
    const int wc = (wid & 3) * 64;
    const int lm = lane & 15;

    const int srow = wid * 8 + (lane >> 3);
    const int scol = ((lane & 7) ^ (lane >> 3)) * 16;      // bytes
    const int pidx0 = (((lane >> 4) + 0) ^ (lane & 7)) * 16;
    const int pidx1 = (((lane >> 4) + 4) ^ (lane & 7)) * 16;

#define STAGE_A(kk_t, buf_t, c) { \
    async_copy16(Xn + (size_t)(i0 + (c) * 64 + srow) * C_DIM + (kk_t) * 128 + scol, \
                 &smA[buf_t][((c) * 64 + wid * 8) * 128]); }

#define STAGE_B(jt_t, kk_t, buf_t, c) { \
    async_copy16(Sn + (size_t)(jbase + (jt_t) * 256 + (c) * 64 + srow) * C_DIM + (kk_t) * 128 + scol, \
                 &smB[buf_t][((c) * 64 + wid * 8) * 128]); }

#define RD_A(QH, BUF) { \
    _Pragma("unroll") \
    for (int m = 0; m < 4; ++m) { \
      aF[m][0] = *(const i64x2*)&smA[BUF][(wr + (QH) * 64 + m * 16 + lm) * 128 + pidx0]; \
      aF[m][1] = *(const i64x2*)&smA[BUF][(wr + (QH) * 64 + m * 16 + lm) * 128 + pidx1]; \
    } }

#define RD_B(NH, BUF) { \
    _Pragma("unroll") \
    for (int n = 0; n < 2; ++n) { \
      bF[n][0] = *(const i64x2*)&smB[BUF][(wc + (NH) * 32 + n * 16 + lm) * 128 + pidx0]; \
      bF[n][1] = *(const i64x2*)&smB[BUF][(wc + (NH) * 32 + n * 16 + lm) * 128 + pidx1]; \
    } }

#define MQ(MH, NH, DOZERO, DORMAX) { \
    if (DOZERO) { \
      _Pragma("unroll") \
      for (int m = 0; m < 4; ++m) \
        _Pragma("unroll") \
        for (int n = 0; n < 2; ++n) \
          acc[(MH) * 4 + m][(NH) * 2 + n] = f32x4{0.f, 0.f, 0.f, 0.f}; \
    } \
    __builtin_amdgcn_s_setprio(1); \
    _Pragma("unroll") \
    for (int P = 0; P < 2; ++P) \
      _Pragma("unroll") \
      for (int h = 0; h < 2; ++h) \
        _Pragma("unroll") \
        for (int m = 0; m < 4; ++m) \
          _Pragma("unroll") \
          for (int n = 0; n < 2; ++n) \
            acc[(MH) * 4 + m][(NH) * 2 + n] = __builtin_amdgcn_mfma_f32_16x16x32_fp8_fp8( \
                aF[m][P][h], bF[n][P][h], acc[(MH) * 4 + m][(NH) * 2 + n], 0, 0, 0); \
    __builtin_amdgcn_s_setprio(0); \
    if (DORMAX) { \
      _Pragma("unroll") \
      for (int m = 0; m < 4; ++m) \
        _Pragma("unroll") \
        for (int r = 0; r < 4; ++r) \
          rmax[(MH) * 4 + m][r] = fmaxf(rmax[(MH) * 4 + m][r], \
              fmaxf(acc[(MH) * 4 + m][(NH) * 2 + 0][r], acc[(MH) * 4 + m][(NH) * 2 + 1][r])); \
    } }

    f32x4 acc[8][4];
    float rmax[8][4];
    i64x2 aF[4][2], bF[2][2];
    #pragma unroll
    for (int m = 0; m < 8; ++m)
        #pragma unroll
        for (int r = 0; r < 4; ++r) rmax[m][r] = -3.0e38f;

    // prologue: A(0)c0-3, B(0)c0-3, A(1)c0,c1 (10 loads); oldest 8 -> vmcnt(2)
    STAGE_A(0, 0, 0); STAGE_A(0, 0, 1); STAGE_A(0, 0, 2); STAGE_A(0, 0, 3);
    STAGE_B(0, 0, 0, 0); STAGE_B(0, 0, 0, 1); STAGE_B(0, 0, 0, 2); STAGE_B(0, 0, 0, 3);
    STAGE_A(1, 1, 0); STAGE_A(1, 1, 1);
    asm volatile("s_waitcnt vmcnt(2)" ::: "memory");
    BARRIER();

    for (int jt = 0; jt < NJT; ++jt) {
        for (int kk = 0; kk < KT; ++kk) {
            const int buf = kk & 1;
            int kk1 = kk + 1, jt1 = jt;
            if (kk1 == KT) { kk1 = 0; jt1 = (jt + 1) & (NJT - 1); }
            int kk2 = kk + 2, jt2 = jt;
            if (kk2 >= KT) { kk2 -= KT; jt2 = (jt + 1) & (NJT - 1); }
            const bool z = (kk == 0), rx = (kk == KT - 1);

            // p0: quad(0,0)
            RD_A(0, buf) RD_B(0, buf)
            STAGE_A(kk1, buf ^ 1, 2); STAGE_A(kk1, buf ^ 1, 3);
            BARRIER();
            MQ(0, 0, z, rx)
            BARRIER();
            // p1: quad(0,1)
            RD_B(1, buf)
            STAGE_B(jt1, kk1, buf ^ 1, 0); STAGE_B(jt1, kk1, buf ^ 1, 1);
            BARRIER();
            MQ(0, 1, z, rx)
            BARRIER();
            // p2: quad(1,1)
            RD_A(1, buf)
            STAGE_B(jt1, kk1, buf ^ 1, 2); STAGE_B(jt1, kk1, buf ^ 1, 3);
            BARRIER();
            MQ(1, 1, z, rx)
            BARRIER();
            // p3: quad(1,0)
            RD_B(0, buf)
            STAGE_A(kk2, buf, 0); STAGE_A(kk2, buf, 1);
            BARRIER();
            MQ(1, 0, z, rx)
            asm volatile("s_waitcnt vmcnt(2)" ::: "memory");
            BARRIER();
        }
    }

    // epilogue: drain all DMA before reusing LDS
    asm volatile("s_waitcnt vmcnt(0) lgkmcnt(0)" ::: "memory");
    BARRIER();

    float* red = (float*)&smA[0][0];   // [4 col-waves][256 rows]
    #pragma unroll
    for (int m8 = 0; m8 < 8; ++m8)
        #pragma unroll
        for (int r = 0; r < 4; ++r) {
            float v = rmax[m8][r];
            v = fmaxf(v, __shfl_xor(v, 1));
            v = fmaxf(v, __shfl_xor(v, 2));
            v = fmaxf(v, __shfl_xor(v, 4));
            v = fmaxf(v, __shfl_xor(v, 8));
            if (lm == 0) {
                const int row_l = wr + (m8 >> 2) * 64 + (m8 & 3) * 16 + (lane >> 4) * 4 + r;
                red[(wid & 3) * 256 + row_l] = v;
            }
        }
    BARRIER();
    if (tid < 256) {
        float v = fmaxf(fmaxf(red[tid], red[256 + tid]),
                        fmaxf(red[512 + tid], red[768 + tid]));
        wmax[(size_t)split * P_DIM + i0 + tid] = v;
    }
}

// --- 4. loss = mean(1 - max/SCALE^2) ---
__global__ void final_reduce(const float* __restrict__ wmax, float* __restrict__ out) {
    __shared__ float red[256];
    int t = threadIdx.x;
    const float isc = 1.0f / (SCALE * SCALE);
    float sum = 0.f;
    for (int i = t; i < P_DIM; i += 256) {
        float m = wmax[i];
        #pragma unroll
        for (int sp = 1; sp < 4; ++sp) m = fmaxf(m, wmax[(size_t)sp * P_DIM + i]);
        sum += 1.0f - m * isc;
    }
    red[t] = sum;
    __syncthreads();
    for (int st = 128; st > 0; st >>= 1) {
        if (t < st) red[t] += red[t + st];
        __syncthreads();
    }
    if (t == 0) out[0] = red[0] * (1.0f / (float)P_DIM);
}

extern "C" void kernel_launch(void* const* d_in, const int* in_sizes, int n_in,
                              void* d_out, int out_size, void* d_ws, size_t ws_size,
                              hipStream_t stream) {
    const float* x = (const float*)d_in[0];
    const float* s = (const float*)d_in[1];
    float* out = (float*)d_out;
    char* ws = (char*)d_ws;

    u8* Xn = (u8*)(ws + OFF_XN);
    u8* Sn = (u8*)(ws + OFF_SN);
    float* invx = (float*)(ws + OFF_INVX);
    float* invs = (float*)(ws + OFF_INVS);
    float* wmax = (float*)(ws + OFF_MAX);

    norm_kernel<<<dim3(16, 2), 256, 0, stream>>>(x, s, invx, invs);
    tnorm_kernel<<<dim3(256, 12, 2), 256, 0, stream>>>(x, s, invx, invs, Xn, Sn);
    nnfm_gemm_max<<<dim3((P_DIM / 256) * JSPLIT), 512, 0, stream>>>(Xn, Sn, wmax);
    final_reduce<<<1, 256, 0, stream>>>(wmax, out);
}